// Round 2
// baseline (390.401 us; speedup 1.0000x reference)
//
#include <hip/hip_runtime.h>

// Problem constants (fixed by the reference file)
constexpr int C = 32;
constexpr int H = 128;
constexpr int W = 512;
constexpr int PAD = 40;
constexpr int D = PAD + 1;     // 41 disparity planes
constexpr int W4 = W / 4;      // 128 float4 per row
constexpr int RPB = 32;        // rows per block
constexpr int QUADS = H / RPB; // 4 row-chunks per plane
constexpr int ITERS = RPB / 2; // 256 threads = 2 rows x 128 float4 per pass

// Native vector type for __builtin_nontemporal_store (HIP float4 is a class
// type the builtin rejects; this is bit-identical).
typedef float f32x4 __attribute__((ext_vector_type(4)));

// out[c][d][h][w] = (w >= d) ? in1[c][h][w] * in2[c][h][w-d] : 0
//
// Inverted decomposition vs original version: one block per (c, d, row-chunk)
// so every block writes a CONTIGUOUS 64 KB stream (original kernel wrote 41
// chunks strided by exactly 256 KB = the L2 way size -> same-set aliasing and
// scattered HBM write-back; measured ~2.7 TB/s effective store BW).
// Inputs (16.8 MB total) are re-read once per d but live entirely in L2/L3,
// so HBM still sees each input byte once. d is block-uniform -> the intra-
// float4 shift rr = d&3 is specialized at compile time via a uniform switch.
template <int RR>
__device__ __forceinline__
void corr_loop(const float4* __restrict__ p1,
               const float4* __restrict__ p2c,
               const float4* __restrict__ p2p,
               float4* po,
               const bool curOk, const bool prevOk) {
    const float4 zero4 = make_float4(0.f, 0.f, 0.f, 0.f);
#pragma unroll 4
    for (int i = 0; i < ITERS; ++i) {
        float4 a   = *p1;
        float4 cur = *p2c;
        float4 prv = (RR == 0) ? zero4 : *p2p;   // RR==0 never uses prv (DCE'd)
        if (!curOk)             cur = zero4;     // whole float4 left of row start
        if (RR != 0 && !prevOk) prv = zero4;

        // b[k] = in2row[4*w4 + k - d]; element (k-RR) of cur if k>=RR,
        // else element (4+k-RR) of prev. RR is compile-time -> free selects.
        float b0, b1, b2, b3;
        if (RR == 0)      { b0 = cur.x; b1 = cur.y; b2 = cur.z; b3 = cur.w; }
        else if (RR == 1) { b0 = prv.w; b1 = cur.x; b2 = cur.y; b3 = cur.z; }
        else if (RR == 2) { b0 = prv.z; b1 = prv.w; b2 = cur.x; b3 = cur.y; }
        else              { b0 = prv.y; b1 = prv.z; b2 = prv.w; b3 = cur.x; }

        f32x4 res;
        res.x = a.x * b0;
        res.y = a.y * b1;
        res.z = a.z * b2;
        res.w = a.w * b3;

        // Output is write-once, never read: stream past the caches so the
        // L2/L3 keep holding the (heavily re-read) inputs.
        __builtin_nontemporal_store(res, (f32x4*)po);

        p1 += 2 * W4; p2c += 2 * W4; p2p += 2 * W4; po += 2 * W4;
    }
}

__global__ __launch_bounds__(256)
void corr1d_kernel(const float* __restrict__ in1,
                   const float* __restrict__ in2,
                   float* __restrict__ out) {
    const int c    = blockIdx.y;                 // [0,32)
    const int d    = blockIdx.x >> 2;            // [0,41)
    const int quad = blockIdx.x & (QUADS - 1);   // [0,4)
    const int t  = threadIdx.x;
    const int r  = t >> 7;                       // row within pair: 0/1
    const int w4 = t & (W4 - 1);                 // float4 slot in row

    const int q  = d >> 2;                       // float4 shift
    const int i0 = w4 - q;
    const bool curOk  = (i0 >= 0);               // per-thread, loop-invariant
    const bool prevOk = (i0 >= 1);
    const int icur  = curOk  ? i0     : 0;       // clamp: stay inside the row
    const int iprev = prevOk ? i0 - 1 : 0;

    const int h = quad * RPB + r;
    const int rowBase = (c * H + h) * W4;
    const float4* p1  = (const float4*)in1 + rowBase + w4;
    const float4* p2c = (const float4*)in2 + rowBase + icur;
    const float4* p2p = (const float4*)in2 + rowBase + iprev;
    float4*       po  = (float4*)out + ((c * D + d) * H + h) * W4 + w4;

    switch (d & 3) {                             // block-uniform branch
        case 0:  corr_loop<0>(p1, p2c, p2p, po, curOk, prevOk); break;
        case 1:  corr_loop<1>(p1, p2c, p2p, po, curOk, prevOk); break;
        case 2:  corr_loop<2>(p1, p2c, p2p, po, curOk, prevOk); break;
        default: corr_loop<3>(p1, p2c, p2p, po, curOk, prevOk); break;
    }
}

extern "C" void kernel_launch(void* const* d_in, const int* in_sizes, int n_in,
                              void* d_out, int out_size, void* d_ws, size_t ws_size,
                              hipStream_t stream) {
    const float* in1 = (const float*)d_in[0];
    const float* in2 = (const float*)d_in[1];
    float* out = (float*)d_out;

    dim3 block(256);
    dim3 grid(D * QUADS, C);   // (164, 32) = 5248 blocks, 64 KB linear write each
    corr1d_kernel<<<grid, block, 0, stream>>>(in1, in2, out);
}

// Round 3
// 362.863 us; speedup vs baseline: 1.0759x; 1.0759x over previous
//
#include <hip/hip_runtime.h>

// Problem constants (fixed by the reference file)
constexpr int C = 32;
constexpr int H = 128;
constexpr int W = 512;
constexpr int PAD = 40;
constexpr int D = PAD + 1;     // 41 disparity planes
constexpr int W4 = W / 4;      // 128 float4 per row
constexpr int ROWS = 16;       // rows per block chunk (H/8)
constexpr int CHUNKS = H / ROWS;  // 8 row chunks
constexpr int NGROUPS = 6;        // d-groups: sizes {7,7,7,7,7,6}

// out[c][d][h][w] = (w >= d) ? in1[c][h][w] * in2[c][h][w-d] : 0
//
// R3 design: bound BOTH failure modes seen so far.
//  - R0 (block owns all 41 d): reads 1x but 41 tiny 4KB strided write streams
//    -> 2.75 TB/s effective store BW (kernel ~125us).
//  - R2 (block owns one d): contiguous writes but 41x input re-reads
//    -> ~1.4GB from Infinity Cache at ~8 TB/s == the whole 172us runtime.
// Here: block = (c, 16-row chunk, d-group of ~7). Read amp only 6x (~250MB,
// L2/L3-resident, ~30us hidden). Writes: 7 streams x 32KB contiguous each.
// PLAIN stores (no nt) — the 6.3TB/s fill proves plain stores are the fast
// write path; this also de-confounds R2's nt suspicion.
// D0 (group base plane) is a template parameter: all float4/element shifts
// fold to compile-time register selects; the 7 planes per group need only a
// 4-float4 sliding window of in2 per row-slice.
template <int D0, int G>
__device__ __forceinline__
void corr_group(const float4* __restrict__ in1v,
                const float4* __restrict__ in2v,
                float4* __restrict__ outv,
                const int c, const int chunk) {
    constexpr int Q0  = D0 >> 2;   // base float4 shift
    constexpr int RR0 = D0 & 3;    // base intra-float4 shift

    const int t  = threadIdx.x;
    const int r  = t >> 7;                 // row within pair: 0/1
    const int w4 = t & (W4 - 1);           // float4 slot in row

    // in2 window float4 indices I, I-1, I-2, I-3 (clamped; zeroed if <0).
    const int I = w4 - Q0;
    const bool ok0 = (I >= 0), ok1 = (I >= 1), ok2 = (I >= 2), ok3 = (I >= 3);
    const int i0 = ok0 ? I     : 0;
    const int i1 = ok1 ? I - 1 : 0;
    const int i2 = ok2 ? I - 2 : 0;
    const int i3 = ok3 ? I - 3 : 0;

    const int h = chunk * ROWS + r;
    const int rowBase = (c * H + h) * W4;

    const float4* p1  = in1v + rowBase + w4;
    const float4* pw0 = in2v + rowBase + i0;
    const float4* pw1 = in2v + rowBase + i1;
    const float4* pw2 = in2v + rowBase + i2;
    const float4* pw3 = in2v + rowBase + i3;
    float4*       po  = outv + ((c * D + D0) * H + h) * W4 + w4;

    const float4 z4 = make_float4(0.f, 0.f, 0.f, 0.f);

#pragma unroll
    for (int s = 0; s < ROWS / 2; ++s) {   // 8 slices of 2 rows
        const float4 a  = *p1;
        const float4 w0 = ok0 ? *pw0 : z4;
        const float4 w1 = ok1 ? *pw1 : z4;
        const float4 w2 = ok2 ? *pw2 : z4;
        const float4 w3 = ok3 ? *pw3 : z4;   // DCE'd for groups not needing it

#pragma unroll
        for (int j = 0; j < G; ++j) {
            // plane d = D0 + j; after unroll everything below is constant-folded
            const int SEL = RR0 + j;
            const int qo  = SEL >> 2;        // extra float4 shift: 0,1,2
            const int rj  = SEL & 3;         // intra-float4 shift

            const float4 cur  = (qo == 0) ? w0 : ((qo == 1) ? w1 : w2);
            const float4 prev = (qo == 0) ? w1 : ((qo == 1) ? w2 : w3);

            // b[k] = in2row[4*w4 + k - d]
            float b0, b1, b2, b3;
            if      (rj == 0) { b0 = cur.x;  b1 = cur.y;  b2 = cur.z;  b3 = cur.w; }
            else if (rj == 1) { b0 = prev.w; b1 = cur.x;  b2 = cur.y;  b3 = cur.z; }
            else if (rj == 2) { b0 = prev.z; b1 = prev.w; b2 = cur.x;  b3 = cur.y; }
            else              { b0 = prev.y; b1 = prev.z; b2 = prev.w; b3 = cur.x; }

            float4 res;
            res.x = a.x * b0;
            res.y = a.y * b1;
            res.z = a.z * b2;
            res.w = a.w * b3;

            po[j * H * W4] = res;            // plain store, plane stride folds to imm-ish
        }

        p1  += 2 * W4;
        pw0 += 2 * W4;  pw1 += 2 * W4;  pw2 += 2 * W4;  pw3 += 2 * W4;
        po  += 2 * W4;
    }
}

__global__ __launch_bounds__(256)
void corr1d_kernel(const float* __restrict__ in1,
                   const float* __restrict__ in2,
                   float* __restrict__ out) {
    const int c     = blockIdx.y;            // [0,32)
    const int g     = blockIdx.x >> 3;       // [0,6) d-group
    const int chunk = blockIdx.x & (CHUNKS - 1); // [0,8) row chunk

    const float4* in1v = (const float4*)in1;
    const float4* in2v = (const float4*)in2;
    float4*       outv = (float4*)out;

    switch (g) {                             // block-uniform; D0 = 7*g
        case 0:  corr_group< 0, 7>(in1v, in2v, outv, c, chunk); break;
        case 1:  corr_group< 7, 7>(in1v, in2v, outv, c, chunk); break;
        case 2:  corr_group<14, 7>(in1v, in2v, outv, c, chunk); break;
        case 3:  corr_group<21, 7>(in1v, in2v, outv, c, chunk); break;
        case 4:  corr_group<28, 7>(in1v, in2v, outv, c, chunk); break;
        default: corr_group<35, 6>(in1v, in2v, outv, c, chunk); break;
    }
}

extern "C" void kernel_launch(void* const* d_in, const int* in_sizes, int n_in,
                              void* d_out, int out_size, void* d_ws, size_t ws_size,
                              hipStream_t stream) {
    const float* in1 = (const float*)d_in[0];
    const float* in2 = (const float*)d_in[1];
    float* out = (float*)d_out;

    dim3 block(256);
    dim3 grid(NGROUPS * CHUNKS, C);   // (48, 32) = 1536 blocks = 6/CU, balanced
    corr1d_kernel<<<grid, block, 0, stream>>>(in1, in2, out);
}